// Round 10
// baseline (1807.798 us; speedup 1.0000x reference)
//
#include <hip/hip_runtime.h>

// VanillaRNN: h_{t+1} = tanh(W_hx x_t + W_hh h_t + b_h), T=1024, H=512, B=256.
// R10 = R9 with the dot engine switched from v_dot2_f32_f16 to v_pk_fma_f16.
// Rate hypothesis (from R9 counters): VALUBusy 77% x 3370 cyc/step = 2595 busy
// cyc/SIMD matches dot2 at 4 cyc/wave64 (half rate), not 2 cyc (would be 40%).
// v_pk_fma_f16 (packed f16, 2 MAC/lane) should be full rate (2 cyc): each
// 4-pair chunk = 4 pk_fma into an f16x2 accumulator + 1 exact fdot2 fold into
// f32 (fold constant (1,1) from SGPR). Instrs 32->35 per row-slice but at
// half the cycles each. Accuracy: 8-term f16 sub-chains add ~1e-4 pre-act
// noise per chunk (<< existing f16 W/h quantization); expect absmax <= 0.008.
// Everything else FROZEN from R9: k-sliced decomposition (wave w owns k-slice
// [64w,64w+64), lane owns 8 rows), W 28 pairs in regs + 4 pairs in LDS b128,
// swizzled f32 partials dbuf, one barrier/step, wave-local hs ring, readlane
// h-broadcast, asm pin, unroll 1.

#define T_SEQ    1024
#define HID      512
#define NTHREADS 512
#define NW       8            // waves
#define NCLS     10
#define RP       8            // rows per thread (dot phase)
#define PAIRS    32           // f16 pairs per wave k-slice (64 k)
#define PREG     28           // pairs 0..27 in VGPRs (224 regs)
#define PSTRIDE  576          // padded part row: 512 + 16*4 pad, 16B-aligned

typedef _Float16 half2_t __attribute__((ext_vector_type(2)));

__device__ __forceinline__ unsigned int pack2(float a, float b) {
    half2_t h = {(_Float16)a, (_Float16)b};
    return __builtin_bit_cast(unsigned int, h);
}

__device__ __forceinline__ float fdot2(half2_t a, half2_t b, float acc) {
#if __has_builtin(__builtin_amdgcn_fdot2)
    return __builtin_amdgcn_fdot2(a, b, acc, false);
#else
    return acc + (float)a.x * (float)b.x + (float)a.y * (float)b.y;
#endif
}

__device__ __forceinline__ unsigned int bcast(unsigned int v, int lane) {
#if __has_builtin(__builtin_amdgcn_readlane)
    return __builtin_amdgcn_readlane(v, lane);   // -> SGPR, uniform
#else
    return __shfl((int)v, lane, 64);
#endif
}

__device__ __forceinline__ half2_t h2(unsigned int u) {
    return __builtin_bit_cast(half2_t, u);
}

// Bank-balanced padded index (multiple-of-4 pad keeps 16 B alignment).
__device__ __forceinline__ int pidx(int row) { return row + ((row >> 5) << 2); }

__device__ __forceinline__ float fast_tanh(float s) {
    // tanh(s) = 1 - 2/(e^{2s}+1); exp2(s*2*log2e). Exact at +/-inf.
#if __has_builtin(__builtin_amdgcn_exp2f)
    float e = __builtin_amdgcn_exp2f(s * 2.885390081777927f);
#else
    float e = __expf(2.0f * s);
#endif
    return 1.0f - 2.0f / (e + 1.0f);
}

__global__ __attribute__((amdgpu_flat_work_group_size(NTHREADS, NTHREADS)))
           __attribute__((amdgpu_waves_per_eu(2, 2)))
void rnn_persist(
    const float* __restrict__ x, const float* __restrict__ h_init,
    const float* __restrict__ W_hx, const float* __restrict__ W_hh,
    const float* __restrict__ b_h, const float* __restrict__ W_ph,
    const float* __restrict__ b_p, float* __restrict__ out)
{
    __shared__ uint4    Wl4[NW * RP * 64];     // 64 KB: pairs 28..31, b128/row
    __shared__ float    part[2][NW][PSTRIDE];  // 36 KB: partials, dbuf, swizzled
    __shared__ float    x_s[T_SEQ];            //  4 KB
    __shared__ _Float16 hs[HID];               //  1 KB: h ring, wave-internal

    const int tid  = threadIdx.x;
    const int b    = blockIdx.x;
    const int w    = tid >> 6;                 // wave = k-slice owner
    const int lane = tid & 63;

    for (int i = tid; i < T_SEQ; i += NTHREADS) x_s[i] = x[(size_t)b * T_SEQ + i];

    const float whx = W_hx[tid];               // reduce phase: thread owns row tid
    const float bh  = b_h[tid];
    const int   pi  = pidx(tid);               // loop-invariant part-read index
    hs[tid] = (_Float16)h_init[tid];

    const half2_t ones = {(_Float16)1.0f, (_Float16)1.0f};

    // Load W slice: rows 8*lane..8*lane+7, cols [64w, 64w+64).
    // Pairs 0..27 -> registers; pairs 28..31 -> Wl4 (one b128 per row).
    unsigned int wreg[RP][PREG];               // 224 regs (arch VGPR + AGPR)
    #pragma unroll
    for (int r = 0; r < RP; ++r) {
        const float4* row = (const float4*)(W_hh + (size_t)(RP * lane + r) * HID + 64 * w);
        #pragma unroll
        for (int q = 0; q < 7; ++q) {          // pairs 0..13
            float4 v = row[q];
            wreg[r][2 * q]     = pack2(v.x, v.y);
            wreg[r][2 * q + 1] = pack2(v.z, v.w);
        }
#if __has_builtin(__builtin_amdgcn_sched_barrier)
        __builtin_amdgcn_sched_barrier(0);
#endif
        #pragma unroll
        for (int q = 7; q < 14; ++q) {         // pairs 14..27
            float4 v = row[q];
            wreg[r][2 * q]     = pack2(v.x, v.y);
            wreg[r][2 * q + 1] = pack2(v.z, v.w);
        }
        float4 v14 = row[14], v15 = row[15];
        Wl4[(w * RP + r) * 64 + lane] =
            make_uint4(pack2(v14.x, v14.y), pack2(v14.z, v14.w),
                       pack2(v15.x, v15.y), pack2(v15.z, v15.w));
#if __has_builtin(__builtin_amdgcn_sched_barrier)
        __builtin_amdgcn_sched_barrier(0);     // keep init-phase pressure low
#endif
    }

    // Opaque identity pin: blocks rematerialization of the packed W values.
    #pragma unroll
    for (int r = 0; r < RP; ++r)
        #pragma unroll
        for (int p = 0; p < PREG; ++p)
            asm volatile("" : "+v"(wreg[r][p]));

    __syncthreads();

    const unsigned int* hs32 = (const unsigned int*)hs;  // pair view
    float hval = 0.0f;

    #pragma unroll 1
    for (int t = 0; t < T_SEQ; ++t) {
        const int buf = t & 1;

        // Wave-internal h ring read first (longest-latency dependency).
        unsigned int hpack = hs32[w * 32 + (lane & 31)];
        const float xw = x_s[t];

        float acc[RP];
        #pragma unroll
        for (int r = 0; r < RP; ++r) acc[r] = 0.0f;

        // Pairs 0..27 in 7 chunks of 4: per (row,chunk) 4 v_pk_fma_f16 into an
        // f16x2 accumulator, then one exact fdot2((1,1)) fold into f32 acc.
        #pragma unroll
        for (int c = 0; c < 7; ++c) {
            half2_t hp0 = h2(bcast(hpack, 4 * c));
            half2_t hp1 = h2(bcast(hpack, 4 * c + 1));
            half2_t hp2 = h2(bcast(hpack, 4 * c + 2));
            half2_t hp3 = h2(bcast(hpack, 4 * c + 3));
            #pragma unroll
            for (int r = 0; r < RP; ++r) {
                half2_t s = h2(wreg[r][4 * c]) * hp0;
                s += h2(wreg[r][4 * c + 1]) * hp1;
                s += h2(wreg[r][4 * c + 2]) * hp2;
                s += h2(wreg[r][4 * c + 3]) * hp3;
                acc[r] = fdot2(s, ones, acc[r]);
            }
        }
        // Pairs 28..31 from LDS (one conflict-free b128 per row), same scheme.
        {
            half2_t hp0 = h2(bcast(hpack, 28));
            half2_t hp1 = h2(bcast(hpack, 29));
            half2_t hp2 = h2(bcast(hpack, 30));
            half2_t hp3 = h2(bcast(hpack, 31));
            #pragma unroll
            for (int r = 0; r < RP; ++r) {
                uint4 wq = Wl4[(w * RP + r) * 64 + lane];
                half2_t s = h2(wq.x) * hp0;
                s += h2(wq.y) * hp1;
                s += h2(wq.z) * hp2;
                s += h2(wq.w) * hp3;
                acc[r] = fdot2(s, ones, acc[r]);
            }
        }

        // Partials for rows 8*lane..8*lane+7, swizzled (bank-balanced b128).
        *(float4*)&part[buf][w][pidx(RP * lane)]     = make_float4(acc[0], acc[1], acc[2], acc[3]);
        *(float4*)&part[buf][w][pidx(RP * lane + 4)] = make_float4(acc[4], acc[5], acc[6], acc[7]);

        __syncthreads();   // partials visible; dbuf => one barrier/step is safe

        // Reduce: thread tid owns row tid; unit-stride b32 reads, conflict-free.
        float s = whx * xw + bh;
        #pragma unroll
        for (int j = 0; j < NW; ++j) s += part[buf][j][pi];

        hval = fast_tanh(s);
        hs[tid] = (_Float16)hval;   // consumed only by this thread's own wave
    }

    // Epilogue: p = W_ph @ h_last + b_p (h_last f32 staged in x_s).
    __syncthreads();
    x_s[tid] = hval;
    __syncthreads();

    for (int c = w; c < NCLS; c += NW) {
        float s = 0.0f;
        #pragma unroll
        for (int j = 0; j < 8; ++j) {
            int r = lane + 64 * j;
            s += W_ph[c * HID + r] * x_s[r];
        }
        #pragma unroll
        for (int off = 32; off; off >>= 1) s += __shfl_down(s, off, 64);
        if (lane == 0) out[b * NCLS + c] = s + b_p[c];
    }
}

extern "C" void kernel_launch(void* const* d_in, const int* in_sizes, int n_in,
                              void* d_out, int out_size, void* d_ws, size_t ws_size,
                              hipStream_t stream) {
    const float* x      = (const float*)d_in[0];
    const float* h_init = (const float*)d_in[1];
    const float* W_hx   = (const float*)d_in[2];
    const float* W_hh   = (const float*)d_in[3];
    const float* b_h    = (const float*)d_in[4];
    const float* W_ph   = (const float*)d_in[5];
    const float* b_p    = (const float*)d_in[6];
    float* out = (float*)d_out;

    const int B = in_sizes[0] / T_SEQ;   // 256 batch columns -> 256 workgroups
    rnn_persist<<<B, NTHREADS, 0, stream>>>(x, h_init, W_hx, W_hh, b_h, W_ph, b_p, out);
}

// Round 11
// 1576.235 us; speedup vs baseline: 1.1469x; 1.1469x over previous
//
#include <hip/hip_runtime.h>

// VanillaRNN: h_{t+1} = tanh(W_hx x_t + W_hh h_t + b_h), T=1024, H=512, B=256.
// R11 = R9 (best, 1438 us) + serial-tail cuts. R10 ruled out pk_fma (same
// issue rate as dot2, more instrs). Floor: 256 dot2/wave @ ~4cyc x 2 waves =
// 2048 cyc/SIMD/step; R9 spent +550 misc +775 stall. This round:
//  1. hs LDS ring -> in-wave shfl exchange: thread tid's hval IS row tid of
//     its own wave's k-slice; hpack = pack2(shfl(h,2*lane), shfl(h,2*lane+1))
//     formed at the reduce tail. Removes the hs write->read LDS round trip
//     (~120 cyc serial latency/step). Only lanes 0..31's hpack is consumed
//     (readlane p, p<32), so upper-half shfl garbage is harmless.
//  2. x_t via uniform scalar load (s_load through sL1): x_s staging removed.
//  3. LDS ~100 KB (still > 80 KB => 1 WG/CU => 2 waves/EU 256-reg budget).
// Frozen from R9: k-sliced decomposition (wave w owns k [64w,64w+64), lane
// owns 8 rows), W 28 pairs in regs + 4 pairs LDS b128, swizzled f32 partials
// dbuf, one barrier/step, readlane h-broadcast, asm pin, unroll 1.

#define T_SEQ    1024
#define HID      512
#define NTHREADS 512
#define NW       8            // waves
#define NCLS     10
#define RP       8            // rows per thread (dot phase)
#define PAIRS    32           // f16 pairs per wave k-slice (64 k)
#define PREG     28           // pairs 0..27 in VGPRs (224 regs)
#define PSTRIDE  576          // padded part row: 512 + 16*4 pad, 16B-aligned

typedef _Float16 half2_t __attribute__((ext_vector_type(2)));

__device__ __forceinline__ unsigned int pack2(float a, float b) {
    half2_t h = {(_Float16)a, (_Float16)b};
    return __builtin_bit_cast(unsigned int, h);
}

__device__ __forceinline__ float dot2(unsigned int w, unsigned int h, float acc) {
#if __has_builtin(__builtin_amdgcn_fdot2)
    return __builtin_amdgcn_fdot2(__builtin_bit_cast(half2_t, w),
                                  __builtin_bit_cast(half2_t, h), acc, false);
#else
    half2_t wv = __builtin_bit_cast(half2_t, w), hv = __builtin_bit_cast(half2_t, h);
    return acc + (float)wv.x * (float)hv.x + (float)wv.y * (float)hv.y;
#endif
}

__device__ __forceinline__ unsigned int bcast(unsigned int v, int lane) {
#if __has_builtin(__builtin_amdgcn_readlane)
    return __builtin_amdgcn_readlane(v, lane);   // -> SGPR, uniform
#else
    return __shfl((int)v, lane, 64);
#endif
}

// Bank-balanced padded index (multiple-of-4 pad keeps 16 B alignment).
__device__ __forceinline__ int pidx(int row) { return row + ((row >> 5) << 2); }

__device__ __forceinline__ float fast_tanh(float s) {
    // tanh(s) = 1 - 2/(e^{2s}+1); exp2(s*2*log2e). Exact at +/-inf.
#if __has_builtin(__builtin_amdgcn_exp2f)
    float e = __builtin_amdgcn_exp2f(s * 2.885390081777927f);
#else
    float e = __expf(2.0f * s);
#endif
    return 1.0f - 2.0f / (e + 1.0f);
}

__global__ __attribute__((amdgpu_flat_work_group_size(NTHREADS, NTHREADS)))
           __attribute__((amdgpu_waves_per_eu(2, 2)))
void rnn_persist(
    const float* __restrict__ x, const float* __restrict__ h_init,
    const float* __restrict__ W_hx, const float* __restrict__ W_hh,
    const float* __restrict__ b_h, const float* __restrict__ W_ph,
    const float* __restrict__ b_p, float* __restrict__ out)
{
    __shared__ uint4 Wl4[NW * RP * 64];        // 64 KB: pairs 28..31, b128/row
    __shared__ float part[2][NW][PSTRIDE];     // 36 KB: partials, dbuf, swizzled

    const int tid  = threadIdx.x;
    const int b    = blockIdx.x;
    const int w    = tid >> 6;                 // wave = k-slice owner
    const int lane = tid & 63;

    const float whx = W_hx[tid];               // reduce phase: thread owns row tid
    const float bh  = b_h[tid];
    const int   pi  = pidx(tid);               // loop-invariant part-read index
    const float* xcol = x + (size_t)b * T_SEQ; // uniform -> scalar loads

    // Load W slice: rows 8*lane..8*lane+7, cols [64w, 64w+64).
    // Pairs 0..27 -> registers; pairs 28..31 -> Wl4 (one b128 per row).
    unsigned int wreg[RP][PREG];               // 224 regs (arch VGPR + AGPR)
    #pragma unroll
    for (int r = 0; r < RP; ++r) {
        const float4* row = (const float4*)(W_hh + (size_t)(RP * lane + r) * HID + 64 * w);
        #pragma unroll
        for (int q = 0; q < 7; ++q) {          // pairs 0..13
            float4 v = row[q];
            wreg[r][2 * q]     = pack2(v.x, v.y);
            wreg[r][2 * q + 1] = pack2(v.z, v.w);
        }
#if __has_builtin(__builtin_amdgcn_sched_barrier)
        __builtin_amdgcn_sched_barrier(0);
#endif
        #pragma unroll
        for (int q = 7; q < 14; ++q) {         // pairs 14..27
            float4 v = row[q];
            wreg[r][2 * q]     = pack2(v.x, v.y);
            wreg[r][2 * q + 1] = pack2(v.z, v.w);
        }
        float4 v14 = row[14], v15 = row[15];
        Wl4[(w * RP + r) * 64 + lane] =
            make_uint4(pack2(v14.x, v14.y), pack2(v14.z, v14.w),
                       pack2(v15.x, v15.y), pack2(v15.z, v15.w));
#if __has_builtin(__builtin_amdgcn_sched_barrier)
        __builtin_amdgcn_sched_barrier(0);     // keep init-phase pressure low
#endif
    }

    // Opaque identity pin: blocks rematerialization of the packed W values.
    #pragma unroll
    for (int r = 0; r < RP; ++r)
        #pragma unroll
        for (int p = 0; p < PREG; ++p)
            asm volatile("" : "+v"(wreg[r][p]));

    __syncthreads();

    // h state: thread tid carries h[tid]; hpack (pairs of this wave's slice,
    // valid in lanes 0..31) is formed in-wave via shfl - no LDS for h.
    float hval = h_init[tid];
    unsigned int hpack = pack2(__shfl(hval, 2 * lane, 64),
                               __shfl(hval, 2 * lane + 1, 64));

    #pragma unroll 1
    for (int t = 0; t < T_SEQ; ++t) {
        const int buf = t & 1;
        const float xw = xcol[t];              // uniform scalar load, off crit path

        float acc[RP];
        #pragma unroll
        for (int r = 0; r < RP; ++r) acc[r] = 0.0f;

        // Pairs 0..27: W from regs, h pair broadcast via readlane -> SGPR.
        #pragma unroll
        for (int p = 0; p < PREG; ++p) {
            unsigned int hp = bcast(hpack, p);
            #pragma unroll
            for (int r = 0; r < RP; ++r) acc[r] = dot2(wreg[r][p], hp, acc[r]);
        }
        // Pairs 28..31: W from LDS, one conflict-free b128 per row.
        {
            unsigned int hh0 = bcast(hpack, 28), hh1 = bcast(hpack, 29),
                         hh2 = bcast(hpack, 30), hh3 = bcast(hpack, 31);
            #pragma unroll
            for (int r = 0; r < RP; ++r) {
                uint4 wq = Wl4[(w * RP + r) * 64 + lane];
                acc[r] = dot2(wq.x, hh0, acc[r]);
                acc[r] = dot2(wq.y, hh1, acc[r]);
                acc[r] = dot2(wq.z, hh2, acc[r]);
                acc[r] = dot2(wq.w, hh3, acc[r]);
            }
        }

        // Partials for rows 8*lane..8*lane+7, swizzled (bank-balanced b128).
        *(float4*)&part[buf][w][pidx(RP * lane)]     = make_float4(acc[0], acc[1], acc[2], acc[3]);
        *(float4*)&part[buf][w][pidx(RP * lane + 4)] = make_float4(acc[4], acc[5], acc[6], acc[7]);

        __syncthreads();   // partials visible; dbuf => one barrier/step is safe

        // Reduce: thread tid owns row tid; unit-stride b32 reads, conflict-free.
        float s = whx * xw + bh;
        #pragma unroll
        for (int j = 0; j < NW; ++j) s += part[buf][j][pi];

        hval = fast_tanh(s);
        // In-wave h exchange: row tid lives in this wave; lanes 0..31 get the
        // pair they feed to readlane next step (upper half unused).
        hpack = pack2(__shfl(hval, 2 * lane, 64),
                      __shfl(hval, 2 * lane + 1, 64));
    }

    // Epilogue: p = W_ph @ h_last + b_p (stage h_last f32 in part[0][0]).
    __syncthreads();
    float* stage = &part[0][0][0];
    stage[tid] = hval;
    __syncthreads();

    for (int c = w; c < NCLS; c += NW) {
        float s = 0.0f;
        #pragma unroll
        for (int j = 0; j < 8; ++j) {
            int r = lane + 64 * j;
            s += W_ph[c * HID + r] * stage[r];
        }
        #pragma unroll
        for (int off = 32; off; off >>= 1) s += __shfl_down(s, off, 64);
        if (lane == 0) out[b * NCLS + c] = s + b_p[c];
    }
}

extern "C" void kernel_launch(void* const* d_in, const int* in_sizes, int n_in,
                              void* d_out, int out_size, void* d_ws, size_t ws_size,
                              hipStream_t stream) {
    const float* x      = (const float*)d_in[0];
    const float* h_init = (const float*)d_in[1];
    const float* W_hx   = (const float*)d_in[2];
    const float* W_hh   = (const float*)d_in[3];
    const float* b_h    = (const float*)d_in[4];
    const float* W_ph   = (const float*)d_in[5];
    const float* b_p    = (const float*)d_in[6];
    float* out = (float*)d_out;

    const int B = in_sizes[0] / T_SEQ;   // 256 batch columns -> 256 workgroups
    rnn_persist<<<B, NTHREADS, 0, stream>>>(x, h_init, W_hx, W_hh, b_h, W_ph, b_p, out);
}